// Round 7
// baseline (136.546 us; speedup 1.0000x reference)
//
#include <hip/hip_runtime.h>
#include <stdint.h>

#define BB 2
#define HH 16
#define TT 2048
#define DD 64
#define NHASH 4
#define NHALF 32   // num_buckets/2

// ---------------- Phase 0: pre-swizzle rotations ----------------
// rot [H][D][N][R] f32  ->  rot_t [H][nr=N*32+R][slot=d4^(r>>2)][4] f32
// (exactly the LDS layout phase 1 consumes; pure bit-move, no arithmetic)
__global__ __launch_bounds__(256) void lsh_rot_transpose_kernel(
    const float* __restrict__ rot,   // [16][64][4][32]
    float4* __restrict__ rot_t)      // [16][2048] float4
{
    const int h    = blockIdx.x >> 3;       // 128 blocks: 16 heads x 8 parts
    const int part = blockIdx.x & 7;
    const int k    = part * 256 + threadIdx.x;  // float4 idx within head [0,2048)
    const int nr   = k >> 4;                // nn*32 + r
    const int slot = k & 15;
    const int r    = nr & 31;
    const int d4   = slot ^ (r >> 2);
    const float* rh = rot + (size_t)h * (DD * NHASH * NHALF);
    float4 o;
    o.x = rh[(d4 * 4 + 0) * 128 + nr];
    o.y = rh[(d4 * 4 + 1) * 128 + nr];
    o.z = rh[(d4 * 4 + 2) * 128 + nr];
    o.w = rh[(d4 * 4 + 3) * 128 + nr];
    rot_t[(size_t)h * 2048 + k] = o;
}

// ---------------- Phase 1: compute packed bucket words ----------------
// grid: BB*HH*(TT/64) = 1024 blocks x 256 threads (4 waves).
// wave = hash n; lane = (tg = lane>>3, rg = lane&7) owns an 8-token x 4-r
// f64 accumulator tile. v and rot staged in LDS as f32 with XOR swizzle
// (slot = d4 ^ rowgroup): conflict-free ds_read_b128, 8-way broadcast.
// f64 accumulation + f32 compare + first-index tie-break matched the np
// reference exactly in rounds 2-6 (absmax 0) — arithmetic untouched here.
__global__ __launch_bounds__(256, 3) void lsh_buckets_kernel(
    const float* __restrict__ hs,      // [BB, TT, HH*DD]
    const float4* __restrict__ rot_t,  // [HH][2048] float4 (pre-swizzled)
    uint32_t* __restrict__ words)      // [BB*HH*TT]
{
    __shared__ uint32_t lds[12288];            // 48 KiB
    float4* v4 = (float4*)lds;                 // [64 t][16 slots]      16 KiB
    float4* r4 = (float4*)(lds + 4096);        // [4 n][32 r][16 slots] 32 KiB

    const int blk  = blockIdx.x;
    const int bh   = blk >> 5;        // / (TT/64)
    const int tblk = blk & 31;
    const int b    = bh >> 4;
    const int h    = bh & 15;
    const int t0   = tblk * 64;
    const int tid  = threadIdx.x;
    const int n    = tid >> 6;        // wave = hash
    const int lane = tid & 63;
    const int tg   = lane >> 3;       // token group (8 tokens)
    const int rg   = lane & 7;        // r group (4 r's)

    // ---- stage v tile: [64 t][64 d] f32, slot = d4 ^ (t>>3) ----
    #pragma unroll
    for (int p = 0; p < 4; ++p) {
        const int k  = tid + p * 256;       // 0..1023 float4s
        const int t  = k >> 4;
        const int d4 = k & 15;
        const float4 f = ((const float4*)(hs + ((size_t)(b * TT + t0 + t)) * (HH * DD) + h * DD))[d4];
        v4[t * 16 + (d4 ^ (t >> 3))] = f;
    }
    // ---- stage rot: linear copy of pre-swizzled layout ----
    {
        const float4* rsrc = rot_t + (size_t)h * 2048;
        #pragma unroll
        for (int p = 0; p < 8; ++p)
            r4[tid + p * 256] = rsrc[tid + p * 256];
    }
    __syncthreads();

    // ---- K loop: acc[i][j] (t = tg*8+i, r = rg*4+j), f64 ----
    double acc[8][4];
    #pragma unroll
    for (int i = 0; i < 8; ++i)
        #pragma unroll
        for (int j = 0; j < 4; ++j) acc[i][j] = 0.0;

    const int vbase = tg * 8 * 16;                 // float4 index of first own token row
    const int rbase = (n * 32 + rg * 4) * 16;      // float4 index of first own r row

    for (int s = 0; s < 16; ++s) {                 // d = s*4 .. s*4+3
        double rd[4][4];
        #pragma unroll
        for (int j = 0; j < 4; ++j) {
            const float4 rf = r4[rbase + j * 16 + (s ^ rg)];
            rd[j][0] = (double)rf.x; rd[j][1] = (double)rf.y;
            rd[j][2] = (double)rf.z; rd[j][3] = (double)rf.w;
        }
        #pragma unroll
        for (int i = 0; i < 8; ++i) {
            const float4 vf = v4[vbase + i * 16 + (s ^ tg)];
            const double v0 = (double)vf.x, v1 = (double)vf.y;
            const double v2 = (double)vf.z, v3 = (double)vf.w;
            #pragma unroll
            for (int j = 0; j < 4; ++j) {
                acc[i][j] += v0 * rd[j][0];
                acc[i][j] += v1 * rd[j][1];
                acc[i][j] += v2 * rd[j][2];
                acc[i][j] += v3 * rd[j][3];
            }
        }
    }

    // ---- epilogue: argmax/argmin over r per (n,t) ----
    __syncthreads();   // all LDS reads done; alias lds for partials
    float*    vmaxL = (float*)lds;            // [4][64][9]
    float*    vminL = (float*)(lds + 2304);
    uint32_t* imaxL = lds + 4608;
    uint32_t* iminL = lds + 6912;

    #pragma unroll
    for (int i = 0; i < 8; ++i) {
        const int t = tg * 8 + i;
        float fmx = -INFINITY; int imx = 0;
        float fmn =  INFINITY; int imn = 0;
        #pragma unroll
        for (int j = 0; j < 4; ++j) {
            const float f = (float)acc[i][j];
            const int   r = rg * 4 + j;
            if (f > fmx) { fmx = f; imx = r; }
            if (f < fmn) { fmn = f; imn = r; }
        }
        const int o = (n * 64 + t) * 9 + rg;
        vmaxL[o] = fmx; vminL[o] = fmn;
        imaxL[o] = (uint32_t)imx; iminL[o] = (uint32_t)imn;
    }
    __syncthreads();
    {
        const int nn = tid >> 6;
        const int t  = tid & 63;
        float fmx = -INFINITY; int imx = 0;
        float fmn =  INFINITY; int imn = 0;
        #pragma unroll
        for (int g = 0; g < 8; ++g) {     // rg ascending -> r ascending: first-index tie-break
            const int o = (nn * 64 + t) * 9 + g;
            const float fx = vmaxL[o];
            const float fn = vminL[o];
            if (fx > fmx) { fmx = fx; imx = (int)imaxL[o]; }
            if (fn < fmn) { fmn = fn; imn = (int)iminL[o]; }
        }
        const uint32_t bucket = (fmx >= -fmn) ? (uint32_t)imx : (uint32_t)(NHALF + imn);
        // words is little-endian: byte nn of word t <- bucket (no pack stage)
        ((uint8_t*)words)[((size_t)bh * TT + t0 + t) * 4 + nn] = (uint8_t)bucket;
    }
}

// ---------------- Phase 2: materialize the [B,H,T,T] mask (int32 0/1) ----------------
#define ROWS 8
__device__ __forceinline__ uint32_t eq_any_byte(uint32_t a, uint32_t b) {
    const uint32_t x = a ^ b;
    return ((x - 0x01010101u) & ~x & 0x80808080u) ? 1u : 0u;
}

__global__ __launch_bounds__(256) void lsh_mask_kernel(
    const uint32_t* __restrict__ words,  // [BB*HH*TT]
    uint4* __restrict__ out)             // [BB*HH*TT][TT/4]
{
    const int bh  = blockIdx.x >> 8;            // TT/ROWS = 256 blocks per bh
    const int i0  = (blockIdx.x & 255) * ROWS;
    const int tid = threadIdx.x;
    const uint32_t* wrow = words + (bh << 11);

    const uint4 wj0 = ((const uint4*)wrow)[tid];        // j = tid*4
    const uint4 wj1 = ((const uint4*)wrow)[tid + 256];  // j = tid*4 + 1024

    #pragma unroll
    for (int k = 0; k < ROWS; ++k) {
        const uint32_t wi = wrow[i0 + k];
        uint4 r0, r1;
        r0.x = eq_any_byte(wi, wj0.x); r0.y = eq_any_byte(wi, wj0.y);
        r0.z = eq_any_byte(wi, wj0.z); r0.w = eq_any_byte(wi, wj0.w);
        r1.x = eq_any_byte(wi, wj1.x); r1.y = eq_any_byte(wi, wj1.y);
        r1.z = eq_any_byte(wi, wj1.z); r1.w = eq_any_byte(wi, wj1.w);
        uint4* op = out + (((size_t)((bh << 11) + i0 + k)) << 9);
        op[tid]       = r0;
        op[tid + 256] = r1;
    }
}

extern "C" void kernel_launch(void* const* d_in, const int* in_sizes, int n_in,
                              void* d_out, int out_size, void* d_ws, size_t ws_size,
                              hipStream_t stream) {
    const float* hs  = (const float*)d_in[0];   // [2, 2048, 1024] f32
    const float* rot = (const float*)d_in[1];   // [16, 64, 4, 32] f32
    uint32_t* words  = (uint32_t*)d_ws;                        // 512 KiB
    float4*   rot_t  = (float4*)((uint8_t*)d_ws + 512 * 1024); // 512 KiB

    lsh_rot_transpose_kernel<<<128, 256, 0, stream>>>(rot, rot_t);
    lsh_buckets_kernel<<<BB * HH * (TT / 64), 256, 0, stream>>>(hs, rot_t, words);
    lsh_mask_kernel<<<BB * HH * (TT / ROWS), 256, 0, stream>>>(words, (uint4*)d_out);
}